// Round 1
// baseline (484.925 us; speedup 1.0000x reference)
//
#include <hip/hip_runtime.h>

#define VOCAB 30000
#define MPAD  30080   // 235 * 128

typedef __attribute__((ext_vector_type(8))) short bf16x8;
typedef __attribute__((ext_vector_type(4))) float f32x4;

__device__ __forceinline__ unsigned short f2bf(float f) {
    unsigned int u = __builtin_bit_cast(unsigned int, f);
    u += 0x7fffu + ((u >> 16) & 1u);          // round-to-nearest-even
    return (unsigned short)(u >> 16);
}
__device__ __forceinline__ float bf2f(unsigned int h) {
    unsigned int u = h << 16;
    return __builtin_bit_cast(float, u);
}

__device__ __forceinline__ void async16(void* g, void* l) {
    __builtin_amdgcn_global_load_lds(
        (__attribute__((address_space(1))) void*)g,
        (__attribute__((address_space(3))) void*)l, 16, 0, 0);
}

// ---------------- prep kernels: build bf16 operands in ws ----------------

// A1[m][k] = bf16(relu(W1[m][k] + b1[k])), rows >= VOCAB zeroed. [MPAD x 512]
__global__ void prep_a1(const float* __restrict__ W1, const float* __restrict__ b1,
                        unsigned short* __restrict__ A1)
{
    const size_t idx = (size_t)blockIdx.x * 256 + threadIdx.x;   // < MPAD*512
    const int m = (int)(idx >> 9);
    const int k = (int)(idx & 511);
    float v = 0.f;
    if (m < VOCAB) v = fmaxf(W1[idx] + b1[k], 0.f);
    A1[idx] = f2bf(v);
}

// W2T[n][k] = bf16(W2[k][n]). [1024 x 512]
__global__ void prep_w2t(const float* __restrict__ W2, unsigned short* __restrict__ W2T)
{
    const int idx = blockIdx.x * 256 + threadIdx.x;   // < 1024*512
    const int n = idx >> 9;
    const int k = idx & 511;
    W2T[idx] = f2bf(W2[k * 1024 + n]);
}

// W3T[n][k] = bf16(W3[k][n]), col 2047 zero-padded. [2048 x 1024]
__global__ void prep_w3t(const float* __restrict__ W3, unsigned short* __restrict__ W3T)
{
    const int idx = blockIdx.x * 256 + threadIdx.x;   // < 2048*1024
    const int n = idx >> 10;
    const int k = idx & 1023;
    float v = 0.f;
    if (n < 2047) v = W3[(size_t)k * 2047 + n];
    W3T[idx] = f2bf(v);
}

// ---------------- m97-style bf16 MFMA GEMM ----------------
// C[M x N] = op(A[M x K] @ BT^T) where BT is [N x K] (B transposed), all bf16 bits.
// Requires M % 128 == 0, N % 128 == 0, K % 32 == 0. No bounds checks.
__global__ __launch_bounds__(256)
void gemm_bf16(const unsigned short* __restrict__ A,
               const unsigned short* __restrict__ BT,
               const float* __restrict__ bias, int bias_n,
               unsigned short* __restrict__ C,
               int K, int N, int relu)
{
    __shared__ __align__(16) unsigned short As[128 * 32];
    __shared__ __align__(16) unsigned short Bs[128 * 32];

    const int tid  = threadIdx.x;
    const int lane = tid & 63;
    const int wid  = tid >> 6;
    const int wr   = wid >> 1;          // wave row 0..1  (64-row span)
    const int wc   = wid & 1;           // wave col 0..1  (64-col span)
    const int m0   = blockIdx.y * 128;
    const int n0   = blockIdx.x * 128;

    const int q  = lane >> 4;           // 0..3
    const int ml = lane & 15;

    f32x4 acc[4][4];
    const f32x4 zero = {0.f, 0.f, 0.f, 0.f};
#pragma unroll
    for (int i = 0; i < 4; ++i)
#pragma unroll
        for (int j = 0; j < 4; ++j) acc[i][j] = zero;

    // staging: 8 chunks of 1 KiB each for As and Bs; wave w stages chunks 2w, 2w+1
    // chunk c = tile rows 16c..16c+15 (32 bf16 = 64 B per row)
    // lane i: row 16c + (i>>2), elem offset (i&3)*8  -> LDS offset i*16 B (HW rule)
    const int sr = lane >> 2;
    const int so = (lane & 3) * 8;

    for (int k0 = 0; k0 < K; k0 += 32) {
#pragma unroll
        for (int cc = 0; cc < 2; ++cc) {
            const int c = 2 * wid + cc;
            const unsigned short* ga = A  + (size_t)(m0 + c * 16 + sr) * K + k0 + so;
            async16((void*)ga, (void*)&As[c * 16 * 32]);
            const unsigned short* gb = BT + (size_t)(n0 + c * 16 + sr) * K + k0 + so;
            async16((void*)gb, (void*)&Bs[c * 16 * 32]);
        }
        __syncthreads();   // drains vmcnt -> LDS tiles ready

        bf16x8 af[4], bfr[4];
#pragma unroll
        for (int t = 0; t < 4; ++t) {
            af[t]  = *(const bf16x8*)&As[(wr * 64 + t * 16 + ml) * 32 + q * 8];
            bfr[t] = *(const bf16x8*)&Bs[(wc * 64 + t * 16 + ml) * 32 + q * 8];
        }
#pragma unroll
        for (int i = 0; i < 4; ++i)
#pragma unroll
            for (int j = 0; j < 4; ++j)
                acc[i][j] = __builtin_amdgcn_mfma_f32_16x16x32_bf16(
                    af[i], bfr[j], acc[i][j], 0, 0, 0);
        __syncthreads();   // protect LDS before next stage
    }

    // epilogue: D col = lane&15, row = (lane>>4)*4 + r  [m89/m91-verified layout]
#pragma unroll
    for (int i = 0; i < 4; ++i) {
#pragma unroll
        for (int j = 0; j < 4; ++j) {
#pragma unroll
            for (int r = 0; r < 4; ++r) {
                const int row = m0 + wr * 64 + i * 16 + q * 4 + r;
                const int col = n0 + wc * 64 + j * 16 + ml;
                float v = acc[i][j][r];
                v += (col < bias_n) ? bias[col] : 0.f;
                if (relu) v = fmaxf(v, 0.f);
                C[(size_t)row * N + col] = f2bf(v);
            }
        }
    }
}

// ---------------- phase B: gather + fused L2-normalize + masked sum ----------------
// One block per batch row b. Thread t owns cols 8t..8t+7 of the 2048-wide row.
__global__ __launch_bounds__(256)
void gather_norm_sum(const int* __restrict__ ingrs, const int* __restrict__ lengths,
                     const unsigned short* __restrict__ Table, float* __restrict__ out)
{
    const int b    = blockIdx.x;
    const int tid  = threadIdx.x;
    const int lane = tid & 63;
    const int wid  = tid >> 6;
    __shared__ float red[4];

    float acc[8];
#pragma unroll
    for (int j = 0; j < 8; ++j) acc[j] = 0.f;

    const int len = lengths[b];   // uniform per block
    for (int l = 0; l < len; ++l) {
        const int id = ingrs[b * 20 + l];
        const uint4 u = *((const uint4*)(Table + (size_t)id * 2048) + tid);
        float v[8];
        v[0] = bf2f(u.x & 0xffffu); v[1] = bf2f(u.x >> 16);
        v[2] = bf2f(u.y & 0xffffu); v[3] = bf2f(u.y >> 16);
        v[4] = bf2f(u.z & 0xffffu); v[5] = bf2f(u.z >> 16);
        v[6] = bf2f(u.w & 0xffffu); v[7] = bf2f(u.w >> 16);

        float s = 0.f;
#pragma unroll
        for (int j = 0; j < 8; ++j) s += v[j] * v[j];
#pragma unroll
        for (int off = 1; off < 64; off <<= 1) s += __shfl_xor(s, off, 64);
        if (lane == 0) red[wid] = s;
        __syncthreads();
        const float tot  = red[0] + red[1] + red[2] + red[3];
        const float invn = 1.0f / fmaxf(sqrtf(tot), 1e-12f);
        __syncthreads();   // red reused next iteration
#pragma unroll
        for (int j = 0; j < 8; ++j) acc[j] += v[j] * invn;
    }

    const size_t base = (size_t)b * 2047;
#pragma unroll
    for (int j = 0; j < 8; ++j) {
        const int col = tid * 8 + j;
        if (col < 2047) out[base + col] = acc[j];
    }
}

// ---------------- launch ----------------

extern "C" void kernel_launch(void* const* d_in, const int* in_sizes, int n_in,
                              void* d_out, int out_size, void* d_ws, size_t ws_size,
                              hipStream_t stream)
{
    const int*   ingrs   = (const int*)d_in[0];
    const int*   lengths = (const int*)d_in[1];
    const float* W1 = (const float*)d_in[2];
    const float* b1 = (const float*)d_in[3];
    const float* W2 = (const float*)d_in[4];
    const float* b2 = (const float*)d_in[5];
    const float* W3 = (const float*)d_in[6];
    const float* b3 = (const float*)d_in[7];
    float* out = (float*)d_out;

    // ws layout (byte offsets, all 16B-aligned):
    //   A1    [MPAD x 512]  bf16 :         0 .. 30,801,920
    //   H2    [MPAD x 1024] bf16 :  30,801,920 .. 92,405,760
    //   Table [MPAD x 2048] bf16 :  92,405,760 .. 215,613,440
    //   W2T   [1024 x 512]  bf16 : 215,613,440 .. 216,662,016
    //   W3T   [2048 x 1024] bf16 : 216,662,016 .. 220,856,320
    char* ws = (char*)d_ws;
    unsigned short* A1    = (unsigned short*)(ws);
    unsigned short* H2    = (unsigned short*)(ws + 30801920);
    unsigned short* Table = (unsigned short*)(ws + 92405760);
    unsigned short* W2T   = (unsigned short*)(ws + 215613440);
    unsigned short* W3T   = (unsigned short*)(ws + 216662016);

    prep_a1 <<<(MPAD * 512) / 256, 256, 0, stream>>>(W1, b1, A1);
    prep_w2t<<<(1024 * 512) / 256, 256, 0, stream>>>(W2, W2T);
    prep_w3t<<<(2048 * 1024) / 256, 256, 0, stream>>>(W3, W3T);

    // H2 = relu(A1 @ W2 + b2)   [MPAD x 1024]
    gemm_bf16<<<dim3(1024 / 128, MPAD / 128), 256, 0, stream>>>(
        A1, W2T, b2, 1024, H2, 512, 1024, 1);
    // Table = A1h2 @ W3 + b3    [MPAD x 2048] (col 2047 is zero pad)
    gemm_bf16<<<dim3(2048 / 128, MPAD / 128), 256, 0, stream>>>(
        H2, W3T, b3, 2047, Table, 1024, 2048, 0);

    gather_norm_sum<<<4096, 256, 0, stream>>>(ingrs, lengths, Table, out);
}

// Round 2
// 457.843 us; speedup vs baseline: 1.0592x; 1.0592x over previous
//
#include <hip/hip_runtime.h>

#define VOCAB 30000
#define MPAD  30080   // 235 * 128

typedef __attribute__((ext_vector_type(8))) short bf16x8;
typedef __attribute__((ext_vector_type(4))) float f32x4;

__device__ __forceinline__ unsigned short f2bf(float f) {
    unsigned int u = __builtin_bit_cast(unsigned int, f);
    u += 0x7fffu + ((u >> 16) & 1u);          // round-to-nearest-even
    return (unsigned short)(u >> 16);
}
__device__ __forceinline__ float bf2f(unsigned int h) {
    unsigned int u = h << 16;
    return __builtin_bit_cast(float, u);
}

__device__ __forceinline__ void async16(const void* g, void* l) {
    __builtin_amdgcn_global_load_lds(
        (__attribute__((address_space(1))) void*)g,
        (__attribute__((address_space(3))) void*)l, 16, 0, 0);
}

// ---------------- prep kernels ----------------

// A1[m][k] = bf16(relu(W1[m][k] + b1[k])), rows >= VOCAB zeroed. [MPAD x 512]
__global__ void prep_a1(const float* __restrict__ W1, const float* __restrict__ b1,
                        unsigned short* __restrict__ A1)
{
    const size_t idx = (size_t)blockIdx.x * 256 + threadIdx.x;   // < MPAD*512
    const int m = (int)(idx >> 9);
    const int k = (int)(idx & 511);
    float v = 0.f;
    if (m < VOCAB) v = fmaxf(W1[idx] + b1[k], 0.f);
    A1[idx] = f2bf(v);
}

// out[n][k] = bf16(in[k][n]); in is [K x Nin] f32, out is [Nout x K] bf16,
// cols n >= Nin zero-padded. K % 64 == 0, Nout % 64 == 0. LDS-tiled, coalesced.
__global__ __launch_bounds__(256)
void transpose_to_bf16(const float* __restrict__ in, unsigned short* __restrict__ out,
                       int K, int Nin)
{
    __shared__ float t[64][65];
    const int n0  = blockIdx.x * 64;
    const int k0  = blockIdx.y * 64;
    const int tid = threadIdx.x;
#pragma unroll
    for (int p = 0; p < 16; ++p) {
        const int lin = p * 256 + tid;
        const int kk = lin >> 6, nn = lin & 63;
        const int n = n0 + nn;
        t[kk][nn] = (n < Nin) ? in[(size_t)(k0 + kk) * Nin + n] : 0.f;
    }
    __syncthreads();
#pragma unroll
    for (int p = 0; p < 16; ++p) {
        const int lin = p * 256 + tid;
        const int nn = lin >> 6, kk = lin & 63;
        out[(size_t)(n0 + nn) * K + k0 + kk] = f2bf(t[kk][nn]);
    }
}

// ---------------- bf16 MFMA GEMM, BK=64, XOR-swizzled LDS ----------------
// C[M x N] = op(A[M x K] @ BT^T); BT is [N x K]. M%128==0, N%128==0, K%64==0.
//
// LDS layout (per 128x64 tile): row r (128 B) holds its 8 16-B k-chunks
// permuted: chunk kc lives at position kc ^ (r & 7). Staging group g = 8 rows
// = 1 KiB; HW writes lane i at group base + 16 B * i, so lane i fetches global
// row g*8+(i>>3), k-chunk (i&7)^((i>>3)&7). Fragment reads land 2-way on
// banks (free) instead of 8-way.
__global__ __launch_bounds__(256)
void gemm_bf16(const unsigned short* __restrict__ A,
               const unsigned short* __restrict__ BT,
               const float* __restrict__ bias, int bias_n,
               unsigned short* __restrict__ C,
               int K, int N, int relu)
{
    __shared__ __align__(16) unsigned short As[128 * 64];
    __shared__ __align__(16) unsigned short Bs[128 * 64];

    const int tid  = threadIdx.x;
    const int lane = tid & 63;
    const int wid  = tid >> 6;
    const int wr   = wid >> 1;          // wave row 0..1 (64-row span)
    const int wc   = wid & 1;           // wave col 0..1 (64-col span)
    const int m0   = blockIdx.y * 128;
    const int n0   = blockIdx.x * 128;

    const int q  = lane >> 4;           // 0..3
    const int ml = lane & 15;

    f32x4 acc[4][4];
    const f32x4 zero = {0.f, 0.f, 0.f, 0.f};
#pragma unroll
    for (int i = 0; i < 4; ++i)
#pragma unroll
        for (int j = 0; j < 4; ++j) acc[i][j] = zero;

    // staging constants: wave w stages groups 4w..4w+3 of A and of B
    const int rg = lane >> 3;                    // row within group, 0..7
    const int kc = (lane & 7) ^ rg;              // swizzled global k-chunk
    const unsigned short* pA = A  + (size_t)(m0 + wid * 32 + rg) * K + kc * 8;
    const unsigned short* pB = BT + (size_t)(n0 + wid * 32 + rg) * K + kc * 8;
    unsigned short* lA = &As[wid * 4 * 512 + lane * 8];
    unsigned short* lB = &Bs[wid * 4 * 512 + lane * 8];

    // fragment-read swizzle: row r -> r&7 == ml&7; chunk index (k32*4+q)
    const int swz0 = (q ^ (ml & 7)) * 8;         // element offset, k32=0; ^32 for k32=1

    for (int k0 = 0; k0 < K; k0 += 64) {
#pragma unroll
        for (int gg = 0; gg < 4; ++gg) {
            async16(pA + (size_t)gg * 8 * K + k0, lA + gg * 512);
            async16(pB + (size_t)gg * 8 * K + k0, lB + gg * 512);
        }
        __syncthreads();   // drains vmcnt -> LDS tiles ready

        bf16x8 af[4], bfr[4];
        // k-half 0
#pragma unroll
        for (int t = 0; t < 4; ++t) {
            af[t]  = *(const bf16x8*)&As[(wr * 64 + t * 16 + ml) * 64 + swz0];
            bfr[t] = *(const bf16x8*)&Bs[(wc * 64 + t * 16 + ml) * 64 + swz0];
        }
#pragma unroll
        for (int i = 0; i < 4; ++i)
#pragma unroll
            for (int j = 0; j < 4; ++j)
                acc[i][j] = __builtin_amdgcn_mfma_f32_16x16x32_bf16(
                    af[i], bfr[j], acc[i][j], 0, 0, 0);
        // k-half 1 (chunk index +4 -> swizzled offset ^ 32 elements)
#pragma unroll
        for (int t = 0; t < 4; ++t) {
            af[t]  = *(const bf16x8*)&As[(wr * 64 + t * 16 + ml) * 64 + (swz0 ^ 32)];
            bfr[t] = *(const bf16x8*)&Bs[(wc * 64 + t * 16 + ml) * 64 + (swz0 ^ 32)];
        }
#pragma unroll
        for (int i = 0; i < 4; ++i)
#pragma unroll
            for (int j = 0; j < 4; ++j)
                acc[i][j] = __builtin_amdgcn_mfma_f32_16x16x32_bf16(
                    af[i], bfr[j], acc[i][j], 0, 0, 0);

        __syncthreads();   // protect LDS before next stage
    }

    // epilogue: D col = lane&15, row = (lane>>4)*4 + r  [m89/m91-verified layout]
#pragma unroll
    for (int i = 0; i < 4; ++i) {
#pragma unroll
        for (int j = 0; j < 4; ++j) {
#pragma unroll
            for (int r = 0; r < 4; ++r) {
                const int row = m0 + wr * 64 + i * 16 + q * 4 + r;
                const int col = n0 + wc * 64 + j * 16 + ml;
                float v = acc[i][j][r];
                v += (col < bias_n) ? bias[col] : 0.f;
                if (relu) v = fmaxf(v, 0.f);
                C[(size_t)row * N + col] = f2bf(v);
            }
        }
    }
}

// ---------------- phase B: gather + fused L2-normalize + masked sum ----------------
__global__ __launch_bounds__(256)
void gather_norm_sum(const int* __restrict__ ingrs, const int* __restrict__ lengths,
                     const unsigned short* __restrict__ Table, float* __restrict__ out)
{
    const int b    = blockIdx.x;
    const int tid  = threadIdx.x;
    const int lane = tid & 63;
    const int wid  = tid >> 6;
    __shared__ float red[4];

    float acc[8];
#pragma unroll
    for (int j = 0; j < 8; ++j) acc[j] = 0.f;

    const int len = lengths[b];   // uniform per block
    for (int l = 0; l < len; ++l) {
        const int id = ingrs[b * 20 + l];
        const uint4 u = *((const uint4*)(Table + (size_t)id * 2048) + tid);
        float v[8];
        v[0] = bf2f(u.x & 0xffffu); v[1] = bf2f(u.x >> 16);
        v[2] = bf2f(u.y & 0xffffu); v[3] = bf2f(u.y >> 16);
        v[4] = bf2f(u.z & 0xffffu); v[5] = bf2f(u.z >> 16);
        v[6] = bf2f(u.w & 0xffffu); v[7] = bf2f(u.w >> 16);

        float s = 0.f;
#pragma unroll
        for (int j = 0; j < 8; ++j) s += v[j] * v[j];
#pragma unroll
        for (int off = 1; off < 64; off <<= 1) s += __shfl_xor(s, off, 64);
        if (lane == 0) red[wid] = s;
        __syncthreads();
        const float tot  = red[0] + red[1] + red[2] + red[3];
        const float invn = 1.0f / fmaxf(sqrtf(tot), 1e-12f);
        __syncthreads();   // red reused next iteration
#pragma unroll
        for (int j = 0; j < 8; ++j) acc[j] += v[j] * invn;
    }

    const size_t base = (size_t)b * 2047;
#pragma unroll
    for (int j = 0; j < 8; ++j) {
        const int col = tid * 8 + j;
        if (col < 2047) out[base + col] = acc[j];
    }
}

// ---------------- launch ----------------

extern "C" void kernel_launch(void* const* d_in, const int* in_sizes, int n_in,
                              void* d_out, int out_size, void* d_ws, size_t ws_size,
                              hipStream_t stream)
{
    const int*   ingrs   = (const int*)d_in[0];
    const int*   lengths = (const int*)d_in[1];
    const float* W1 = (const float*)d_in[2];
    const float* b1 = (const float*)d_in[3];
    const float* W2 = (const float*)d_in[4];
    const float* b2 = (const float*)d_in[5];
    const float* W3 = (const float*)d_in[6];
    const float* b3 = (const float*)d_in[7];
    float* out = (float*)d_out;

    // ws layout (byte offsets, all 16B-aligned):
    //   A1    [MPAD x 512]  bf16 :         0 .. 30,801,920
    //   H2    [MPAD x 1024] bf16 :  30,801,920 .. 92,405,760
    //   Table [MPAD x 2048] bf16 :  92,405,760 .. 215,613,440
    //   W2T   [1024 x 512]  bf16 : 215,613,440 .. 216,662,016
    //   W3T   [2048 x 1024] bf16 : 216,662,016 .. 220,856,320
    char* ws = (char*)d_ws;
    unsigned short* A1    = (unsigned short*)(ws);
    unsigned short* H2    = (unsigned short*)(ws + 30801920);
    unsigned short* Table = (unsigned short*)(ws + 92405760);
    unsigned short* W2T   = (unsigned short*)(ws + 215613440);
    unsigned short* W3T   = (unsigned short*)(ws + 216662016);

    prep_a1<<<(MPAD * 512) / 256, 256, 0, stream>>>(W1, b1, A1);
    // W2 [512 x 1024] -> W2T [1024 x 512]
    transpose_to_bf16<<<dim3(1024 / 64, 512 / 64), 256, 0, stream>>>(W2, W2T, 512, 1024);
    // W3 [1024 x 2047] -> W3T [2048 x 1024], col 2047 zero-padded
    transpose_to_bf16<<<dim3(2048 / 64, 1024 / 64), 256, 0, stream>>>(W3, W3T, 1024, 2047);

    // H2 = relu(A1 @ W2 + b2)   [MPAD x 1024]
    gemm_bf16<<<dim3(1024 / 128, MPAD / 128), 256, 0, stream>>>(
        A1, W2T, b2, 1024, H2, 512, 1024, 1);
    // Table = H2 @ W3 + b3      [MPAD x 2048] (col 2047 is zero pad)
    gemm_bf16<<<dim3(2048 / 128, MPAD / 128), 256, 0, stream>>>(
        H2, W3T, b3, 2047, Table, 1024, 2048, 0);

    gather_norm_sum<<<4096, 256, 0, stream>>>(ingrs, lengths, Table, out);
}

// Round 3
// 385.505 us; speedup vs baseline: 1.2579x; 1.1876x over previous
//
#include <hip/hip_runtime.h>

#define VOCAB 30000
#define MPAD  30080   // 235 * 128

typedef __attribute__((ext_vector_type(8))) short bf16x8;
typedef __attribute__((ext_vector_type(4))) float f32x4;

__device__ __forceinline__ unsigned short f2bf(float f) {
    unsigned int u = __builtin_bit_cast(unsigned int, f);
    u += 0x7fffu + ((u >> 16) & 1u);          // round-to-nearest-even
    return (unsigned short)(u >> 16);
}
__device__ __forceinline__ float bf2f(unsigned int h) {
    unsigned int u = h << 16;
    return __builtin_bit_cast(float, u);
}

__device__ __forceinline__ void async16(const void* g, void* l) {
    __builtin_amdgcn_global_load_lds(
        (__attribute__((address_space(1))) void*)g,
        (__attribute__((address_space(3))) void*)l, 16, 0, 0);
}

// ---------------- compaction: which vocab ids actually occur? ----------------

// flags[0..VOCAB)=0, *cnt=0   (ws is poisoned 0xAA before every call)
__global__ void comp_init(int* __restrict__ flags, int* __restrict__ cnt)
{
    const int i = blockIdx.x * 256 + threadIdx.x;
    if (i < VOCAB) flags[i] = 0;
    if (i == 0) *cnt = 0;
}

// mark ids of valid tokens (plain racing stores of 1 are fine)
__global__ void comp_mark(const int* __restrict__ ingrs, const int* __restrict__ lengths,
                          int* __restrict__ flags)
{
    const int i = blockIdx.x * 256 + threadIdx.x;   // < 4096*20
    if (i >= 4096 * 20) return;
    const int b = i / 20;
    const int l = i - b * 20;
    if (l < lengths[b]) flags[ingrs[i]] = 1;
}

// assign compact slots (order irrelevant -> atomicAdd, no prefix sum)
__global__ void comp_assign(int* __restrict__ flags, int* __restrict__ remap,
                            int* __restrict__ cnt)
{
    const int i = blockIdx.x * 256 + threadIdx.x;
    if (i < VOCAB && flags[i]) remap[i] = atomicAdd(cnt, 1);
}

// ---------------- prep kernels ----------------

// A1[remap[id]][k] = bf16(relu(W1[id][k] + b1[k])) for flagged ids.
// 2 rows per block; thread handles 4 consecutive k.
__global__ __launch_bounds__(256)
void prep_a1c(const float* __restrict__ W1, const float* __restrict__ b1,
              const int* __restrict__ flags, const int* __restrict__ remap,
              unsigned short* __restrict__ A1)
{
    const int tid = threadIdx.x;
    const int id  = blockIdx.x * 2 + (tid >> 7);     // < VOCAB
    if (!flags[id]) return;
    const int row = remap[id];
    const int k4  = (tid & 127) * 4;
    const float4 w = *(const float4*)(W1 + (size_t)id * 512 + k4);
    const float4 bb = *(const float4*)(b1 + k4);
    unsigned short o[4];
    o[0] = f2bf(fmaxf(w.x + bb.x, 0.f));
    o[1] = f2bf(fmaxf(w.y + bb.y, 0.f));
    o[2] = f2bf(fmaxf(w.z + bb.z, 0.f));
    o[3] = f2bf(fmaxf(w.w + bb.w, 0.f));
    *(uint2*)(A1 + (size_t)row * 512 + k4) = *(const uint2*)o;
}

// zero-fill A1 rows [cnt, round128(cnt)) so GEMM1's last M-block reads zeros
__global__ void prep_a1pad(const int* __restrict__ cnt, unsigned short* __restrict__ A1)
{
    const int c  = *cnt;
    const int mc = (c + 127) & ~127;
    const int row = c + blockIdx.x;
    if (row >= mc) return;
    ((unsigned int*)(A1 + (size_t)row * 512))[threadIdx.x] = 0u;   // 256 thr * 4 B = 1 row
}

// out[n][k] = bf16(in[k][n]); in is [K x Nin] f32, out is [Nout x K] bf16,
// cols n >= Nin zero-padded. K % 64 == 0, Nout % 64 == 0. LDS-tiled, coalesced.
__global__ __launch_bounds__(256)
void transpose_to_bf16(const float* __restrict__ in, unsigned short* __restrict__ out,
                       int K, int Nin)
{
    __shared__ float t[64][65];
    const int n0  = blockIdx.x * 64;
    const int k0  = blockIdx.y * 64;
    const int tid = threadIdx.x;
#pragma unroll
    for (int p = 0; p < 16; ++p) {
        const int lin = p * 256 + tid;
        const int kk = lin >> 6, nn = lin & 63;
        const int n = n0 + nn;
        t[kk][nn] = (n < Nin) ? in[(size_t)(k0 + kk) * Nin + n] : 0.f;
    }
    __syncthreads();
#pragma unroll
    for (int p = 0; p < 16; ++p) {
        const int lin = p * 256 + tid;
        const int nn = lin >> 6, kk = lin & 63;
        out[(size_t)(n0 + nn) * K + k0 + kk] = f2bf(t[kk][nn]);
    }
}

// ---------------- bf16 MFMA GEMM, BK=64, XOR-swizzled LDS, M early-exit ----
// C[M x N] = op(A[M x K] @ BT^T); BT is [N x K]. N%128==0, K%64==0.
// Effective M = round128(*cnt); blocks above it exit immediately.
__global__ __launch_bounds__(256)
void gemm_bf16(const unsigned short* __restrict__ A,
               const unsigned short* __restrict__ BT,
               const float* __restrict__ bias, int bias_n,
               unsigned short* __restrict__ C,
               int K, int N, int relu, const int* __restrict__ cnt)
{
    const int m0 = blockIdx.y * 128;
    const int mc = (*cnt + 127) & ~127;
    if (m0 >= mc) return;

    __shared__ __align__(16) unsigned short As[128 * 64];
    __shared__ __align__(16) unsigned short Bs[128 * 64];

    const int tid  = threadIdx.x;
    const int lane = tid & 63;
    const int wid  = tid >> 6;
    const int wr   = wid >> 1;          // wave row 0..1 (64-row span)
    const int wc   = wid & 1;           // wave col 0..1 (64-col span)
    const int n0   = blockIdx.x * 128;

    const int q  = lane >> 4;           // 0..3
    const int ml = lane & 15;

    f32x4 acc[4][4];
    const f32x4 zero = {0.f, 0.f, 0.f, 0.f};
#pragma unroll
    for (int i = 0; i < 4; ++i)
#pragma unroll
        for (int j = 0; j < 4; ++j) acc[i][j] = zero;

    // staging: wave w stages groups 4w..4w+3 (8 rows each) of A and of B.
    // LDS row r holds its 8 16-B k-chunks permuted: chunk kc at pos kc^(r&7).
    const int rg = lane >> 3;                    // row within group, 0..7
    const int kc = (lane & 7) ^ rg;              // swizzled global k-chunk
    const unsigned short* pA = A  + (size_t)(m0 + wid * 32 + rg) * K + kc * 8;
    const unsigned short* pB = BT + (size_t)(n0 + wid * 32 + rg) * K + kc * 8;
    unsigned short* lA = &As[wid * 4 * 512 + lane * 8];
    unsigned short* lB = &Bs[wid * 4 * 512 + lane * 8];

    // fragment-read swizzle: chunk index (k32*4+q) ^ (row&7), row&7 == ml&7
    const int swz0 = (q ^ (ml & 7)) * 8;         // k-half 0; ^32 elems for half 1

    for (int k0 = 0; k0 < K; k0 += 64) {
#pragma unroll
        for (int gg = 0; gg < 4; ++gg) {
            async16(pA + (size_t)gg * 8 * K + k0, lA + gg * 512);
            async16(pB + (size_t)gg * 8 * K + k0, lB + gg * 512);
        }
        __syncthreads();   // drains vmcnt -> LDS tiles ready

        bf16x8 af[4], bfr[4];
#pragma unroll
        for (int t = 0; t < 4; ++t) {
            af[t]  = *(const bf16x8*)&As[(wr * 64 + t * 16 + ml) * 64 + swz0];
            bfr[t] = *(const bf16x8*)&Bs[(wc * 64 + t * 16 + ml) * 64 + swz0];
        }
#pragma unroll
        for (int i = 0; i < 4; ++i)
#pragma unroll
            for (int j = 0; j < 4; ++j)
                acc[i][j] = __builtin_amdgcn_mfma_f32_16x16x32_bf16(
                    af[i], bfr[j], acc[i][j], 0, 0, 0);
#pragma unroll
        for (int t = 0; t < 4; ++t) {
            af[t]  = *(const bf16x8*)&As[(wr * 64 + t * 16 + ml) * 64 + (swz0 ^ 32)];
            bfr[t] = *(const bf16x8*)&Bs[(wc * 64 + t * 16 + ml) * 64 + (swz0 ^ 32)];
        }
#pragma unroll
        for (int i = 0; i < 4; ++i)
#pragma unroll
            for (int j = 0; j < 4; ++j)
                acc[i][j] = __builtin_amdgcn_mfma_f32_16x16x32_bf16(
                    af[i], bfr[j], acc[i][j], 0, 0, 0);

        __syncthreads();   // protect LDS before next stage
    }

    // epilogue: D col = lane&15, row = (lane>>4)*4 + r  [m89/m91-verified layout]
#pragma unroll
    for (int i = 0; i < 4; ++i) {
#pragma unroll
        for (int j = 0; j < 4; ++j) {
#pragma unroll
            for (int r = 0; r < 4; ++r) {
                const int row = m0 + wr * 64 + i * 16 + q * 4 + r;
                const int col = n0 + wc * 64 + j * 16 + ml;
                float v = acc[i][j][r];
                v += (col < bias_n) ? bias[col] : 0.f;
                if (relu) v = fmaxf(v, 0.f);
                C[(size_t)row * N + col] = f2bf(v);
            }
        }
    }
}

// ---------------- phase B: gather (via remap) + L2-normalize + masked sum ----
__global__ __launch_bounds__(256)
void gather_norm_sum(const int* __restrict__ ingrs, const int* __restrict__ lengths,
                     const int* __restrict__ remap,
                     const unsigned short* __restrict__ Table, float* __restrict__ out)
{
    const int b    = blockIdx.x;
    const int tid  = threadIdx.x;
    const int lane = tid & 63;
    const int wid  = tid >> 6;
    __shared__ float red[4];

    float acc[8];
#pragma unroll
    for (int j = 0; j < 8; ++j) acc[j] = 0.f;

    const int len = lengths[b];   // uniform per block
    for (int l = 0; l < len; ++l) {
        const int slot = remap[ingrs[b * 20 + l]];
        const uint4 u = *((const uint4*)(Table + (size_t)slot * 2048) + tid);
        float v[8];
        v[0] = bf2f(u.x & 0xffffu); v[1] = bf2f(u.x >> 16);
        v[2] = bf2f(u.y & 0xffffu); v[3] = bf2f(u.y >> 16);
        v[4] = bf2f(u.z & 0xffffu); v[5] = bf2f(u.z >> 16);
        v[6] = bf2f(u.w & 0xffffu); v[7] = bf2f(u.w >> 16);

        float s = 0.f;
#pragma unroll
        for (int j = 0; j < 8; ++j) s += v[j] * v[j];
#pragma unroll
        for (int off = 1; off < 64; off <<= 1) s += __shfl_xor(s, off, 64);
        if (lane == 0) red[wid] = s;
        __syncthreads();
        const float tot  = red[0] + red[1] + red[2] + red[3];
        const float invn = 1.0f / fmaxf(sqrtf(tot), 1e-12f);
        __syncthreads();   // red reused next iteration
#pragma unroll
        for (int j = 0; j < 8; ++j) acc[j] += v[j] * invn;
    }

    const size_t base = (size_t)b * 2047;
#pragma unroll
    for (int j = 0; j < 8; ++j) {
        const int col = tid * 8 + j;
        if (col < 2047) out[base + col] = acc[j];
    }
}

// ---------------- launch ----------------

extern "C" void kernel_launch(void* const* d_in, const int* in_sizes, int n_in,
                              void* d_out, int out_size, void* d_ws, size_t ws_size,
                              hipStream_t stream)
{
    const int*   ingrs   = (const int*)d_in[0];
    const int*   lengths = (const int*)d_in[1];
    const float* W1 = (const float*)d_in[2];
    const float* b1 = (const float*)d_in[3];
    const float* W2 = (const float*)d_in[4];
    const float* b2 = (const float*)d_in[5];
    const float* W3 = (const float*)d_in[6];
    const float* b3 = (const float*)d_in[7];
    float* out = (float*)d_out;

    // ws layout (byte offsets, 16B-aligned):
    //   A1    [MPAD x 512]  bf16 :           0 ..  30,801,920
    //   H2    [MPAD x 1024] bf16 :  30,801,920 ..  92,405,760
    //   Table [MPAD x 2048] bf16 :  92,405,760 .. 215,613,440
    //   W2T   [1024 x 512]  bf16 : 215,613,440 .. 216,662,016
    //   W3T   [2048 x 1024] bf16 : 216,662,016 .. 220,856,320
    //   flags [VOCAB] int        : 220,856,320 .. 220,976,320
    //   remap [VOCAB] int        : 220,976,320 .. 221,096,320
    //   cnt   [1] int            : 221,096,320 .. 221,096,324
    char* ws = (char*)d_ws;
    unsigned short* A1    = (unsigned short*)(ws);
    unsigned short* H2    = (unsigned short*)(ws + 30801920);
    unsigned short* Table = (unsigned short*)(ws + 92405760);
    unsigned short* W2T   = (unsigned short*)(ws + 215613440);
    unsigned short* W3T   = (unsigned short*)(ws + 216662016);
    int*            flags = (int*)(ws + 220856320);
    int*            remap = (int*)(ws + 220976320);
    int*            cnt   = (int*)(ws + 221096320);

    comp_init  <<<(VOCAB + 255) / 256, 256, 0, stream>>>(flags, cnt);
    comp_mark  <<<(4096 * 20 + 255) / 256, 256, 0, stream>>>(ingrs, lengths, flags);
    comp_assign<<<(VOCAB + 255) / 256, 256, 0, stream>>>(flags, remap, cnt);

    prep_a1c  <<<VOCAB / 2, 256, 0, stream>>>(W1, b1, flags, remap, A1);
    prep_a1pad<<<127, 256, 0, stream>>>(cnt, A1);
    // W2 [512 x 1024] -> W2T [1024 x 512]
    transpose_to_bf16<<<dim3(1024 / 64, 512 / 64), 256, 0, stream>>>(W2, W2T, 512, 1024);
    // W3 [1024 x 2047] -> W3T [2048 x 1024], col 2047 zero-padded
    transpose_to_bf16<<<dim3(2048 / 64, 1024 / 64), 256, 0, stream>>>(W3, W3T, 1024, 2047);

    // H2 = relu(A1 @ W2 + b2)   [mc x 1024]
    gemm_bf16<<<dim3(1024 / 128, MPAD / 128), 256, 0, stream>>>(
        A1, W2T, b2, 1024, H2, 512, 1024, 1, cnt);
    // Table = H2 @ W3 + b3      [mc x 2048] (col 2047 is zero pad)
    gemm_bf16<<<dim3(2048 / 128, MPAD / 128), 256, 0, stream>>>(
        H2, W3T, b3, 2047, Table, 1024, 2048, 0, cnt);

    gather_norm_sum<<<4096, 256, 0, stream>>>(ingrs, lengths, remap, Table, out);
}